// Round 10
// baseline (388.463 us; speedup 1.0000x reference)
//
#include <hip/hip_runtime.h>
#include <hip/hip_fp16.h>

#define BN_EPS 1e-5f
#define HCHUNK 2048           // edges per histogram block
#define SCHUNK 8192           // edges per scatter block (= 4 hist chunks)
#define BBITS 9               // 512 nodes per bucket

typedef _Float16 half8 __attribute__((ext_vector_type(8)));
typedef float f32x4 __attribute__((ext_vector_type(4)));

__device__ __forceinline__ float4 f4zero() { return make_float4(0.f, 0.f, 0.f, 0.f); }

// ---------------- GEMM body: C[n,128](f16) = (A @ W) [* dinv[row] if SCALE] ----------------
// WF32: stage W into LDS fragment order directly from f32 (self-packing, no pW dependency).

template <bool AF32, bool WF32, bool SCALE>
__device__ __forceinline__ void gemm_body(int bid, int tid, char* smem,
                                          const void* __restrict__ Av,
                                          const void* __restrict__ Wv_,
                                          const float* __restrict__ dinv,
                                          uint4* __restrict__ C, int n) {
    uint4* sW = (uint4*)smem;
    if (WF32) {
        const float* Wf = (const float*)Wv_;
#pragma unroll
        for (int i = 0; i < 8; ++i) {
            int t = tid + 256 * i;                 // 0..2047 half8 slots
            int kc = t >> 9, rem = t & 511;
            int ct = rem >> 6, lane = rem & 63;
            int q = lane >> 4, col = ct * 16 + (lane & 15);
            half8 hh;
#pragma unroll
            for (int j = 0; j < 8; ++j)
                hh[j] = (_Float16)Wf[(kc * 32 + q * 8 + j) * 128 + col];
            ((half8*)sW)[t] = hh;
        }
    } else {
        const uint4* gW = (const uint4*)Wv_;
#pragma unroll
        for (int i = 0; i < 8; ++i) sW[tid + 256 * i] = gW[tid + 256 * i];
    }
    __syncthreads();

    int wave = tid >> 6, lane = tid & 63;
    int quad = lane >> 4, l16 = lane & 15;
    int row0 = bid * 64 + wave * 16;
    int arow = row0 + l16;
    int arowc = (arow < n) ? arow : (n - 1);

    half8 af[4];
    if (AF32) {
        const float* A = (const float*)Av + (size_t)arowc * 128 + quad * 8;
#pragma unroll
        for (int kc = 0; kc < 4; ++kc) {
            float4 lo = *(const float4*)(A + kc * 32);
            float4 hi = *(const float4*)(A + kc * 32 + 4);
            half8 h;
            h[0] = (_Float16)lo.x; h[1] = (_Float16)lo.y;
            h[2] = (_Float16)lo.z; h[3] = (_Float16)lo.w;
            h[4] = (_Float16)hi.x; h[5] = (_Float16)hi.y;
            h[6] = (_Float16)hi.z; h[7] = (_Float16)hi.w;
            af[kc] = h;
        }
    } else {
        const _Float16* A = (const _Float16*)Av + (size_t)arowc * 128 + quad * 8;
#pragma unroll
        for (int kc = 0; kc < 4; ++kc)
            af[kc] = *(const half8*)(A + kc * 32);
    }

    f32x4 acc[8];
#pragma unroll
    for (int ct = 0; ct < 8; ++ct) acc[ct] = (f32x4){0.f, 0.f, 0.f, 0.f};

#pragma unroll
    for (int kc = 0; kc < 4; ++kc) {
#pragma unroll
        for (int ct = 0; ct < 8; ++ct) {
            half8 bf = *(half8*)&sW[(kc * 8 + ct) * 64 + lane];
            acc[ct] = __builtin_amdgcn_mfma_f32_16x16x32_f16(af[kc], bf, acc[ct], 0, 0, 0);
        }
    }

    __syncthreads();

    _Float16* eb = (_Float16*)smem + wave * 16 * 136;   // 136 halfs = 272 B row stride
    float dv[4];
#pragma unroll
    for (int r = 0; r < 4; ++r) {
        if (SCALE) {
            int rr = row0 + quad * 4 + r;
            dv[r] = dinv[(rr < n) ? rr : (n - 1)];
        } else dv[r] = 1.f;
    }
#pragma unroll
    for (int ct = 0; ct < 8; ++ct)
#pragma unroll
        for (int r = 0; r < 4; ++r)
            eb[(quad * 4 + r) * 136 + ct * 16 + l16] =
                (_Float16)(SCALE ? acc[ct][r] * dv[r] : acc[ct][r]);

#pragma unroll
    for (int i = 0; i < 4; ++i) {
        int linear = i * 64 + lane;
        int r = linear >> 4, c = linear & 15;
        uint4 v = *(uint4*)((char*)eb + r * 272 + c * 16);
        int row = row0 + r;
        if (row < n) C[(size_t)row * 16 + c] = v;
    }
}

// ---------------- K1: hist (782 blk) ∥ layer-1 GEMM self-pack (1563 blk) ∥ pack W2/W3 ------

__global__ __launch_bounds__(256) void k_hist_gemm1(const int* __restrict__ dst,
                                                    int* __restrict__ tableT,
                                                    int nA2, int nbuck, int e,
                                                    const float* __restrict__ x,
                                                    const float* __restrict__ W1,
                                                    const float* __restrict__ W2,
                                                    const float* __restrict__ W3,
                                                    _Float16* __restrict__ pW,
                                                    uint4* __restrict__ C,
                                                    int n, int gGemm) {
    __shared__ char smem[32768];
    int tid = threadIdx.x;
    int b = blockIdx.x;
    if (b < nA2) {                         // histogram, 2048 edges
        int* h = (int*)smem;
        h[tid] = 0;
        __syncthreads();
        int base = b * HCHUNK;
        if (base + HCHUNK <= e) {
            const int4* d4 = (const int4*)(dst + base);
            int4 d0 = d4[tid];
            int4 d1 = d4[tid + 256];
            atomicAdd(&h[d0.x >> BBITS], 1);
            atomicAdd(&h[d0.y >> BBITS], 1);
            atomicAdd(&h[d0.z >> BBITS], 1);
            atomicAdd(&h[d0.w >> BBITS], 1);
            atomicAdd(&h[d1.x >> BBITS], 1);
            atomicAdd(&h[d1.y >> BBITS], 1);
            atomicAdd(&h[d1.z >> BBITS], 1);
            atomicAdd(&h[d1.w >> BBITS], 1);
        } else {
            for (int i = base + tid; i < e; i += 256)
                atomicAdd(&h[dst[i] >> BBITS], 1);
        }
        __syncthreads();
        for (int k = tid; k < nbuck; k += 256)
            tableT[(size_t)k * nA2 + b] = h[k];
        return;
    }
    b -= nA2;
    if (b < gGemm) {                       // layer-1 GEMM: A=f32 x, W self-packed from f32 W1
        gemm_body<true, true, false>(b, tid, smem, x, W1, nullptr, C, n);
        return;
    }
    // pack W2/W3 -> pW (+16384 / +32768 half offsets)
    int t = (b - gGemm) * 256 + tid;       // 0..4095
    int wi = t >> 11;
    const float* W = wi ? W3 : W2;
    int tt = t & 2047;
    int kc = tt >> 9, rem = tt & 511;
    int ct = rem >> 6, lane = rem & 63;
    int q = lane >> 4, col = ct * 16 + (lane & 15);
    half8 hh;
#pragma unroll
    for (int j = 0; j < 8; ++j)
        hh[j] = (_Float16)W[(kc * 32 + q * 8 + j) * 128 + col];
    *(half8*)(pW + 16384 + (size_t)t * 8) = hh;
}

// ---------------- K2/K3: 2-op exclusive scan of tableT ----------------

__global__ __launch_bounds__(1024) void k_scan_block(const int* __restrict__ in,
                                                     int* __restrict__ outp,
                                                     int* __restrict__ partials, int len) {
    __shared__ int s[1024];
    int t = threadIdx.x;
    int gid = blockIdx.x * 1024 + t;
    int v = (gid < len) ? in[gid] : 0;
    int x = v;
    s[t] = x;
    __syncthreads();
    for (int d = 1; d < 1024; d <<= 1) {
        int y = (t >= d) ? s[t - d] : 0;
        __syncthreads();
        x += y;
        s[t] = x;
        __syncthreads();
    }
    if (gid < len) outp[gid] = x - v;
    if (t == 1023) partials[blockIdx.x] = x;
}

__global__ __launch_bounds__(256) void k_scan_addp(int* __restrict__ data,
                                                   const int* __restrict__ partials, int len) {
    __shared__ int red[256];
    int tid = threadIdx.x;
    int K = blockIdx.x >> 2;          // number of preceding 1024-segments
    int s = 0;
    for (int t = tid; t < K; t += 256) s += partials[t];
    red[tid] = s;
    __syncthreads();
    for (int d = 128; d > 0; d >>= 1) {
        if (tid < d) red[tid] += red[tid + d];
        __syncthreads();
    }
    int gid = blockIdx.x * 256 + tid;
    if (gid < len) data[gid] += red[0];
}

// ---------------- K4: bucket-grouped COO scatter (LDS cursors, 1024 thr, 4 chunks) --------
// Scan continuity across consecutive chunks lets one block process 4 hist-chunks with
// cursors seeded at chunk 4*blk — no syncs needed, atomic cursors cover the whole range.

__global__ __launch_bounds__(1024) void k_scatter(const int* __restrict__ src,
                                                  const int* __restrict__ dst,
                                                  const int* __restrict__ tableT,
                                                  int2* __restrict__ bed,
                                                  int nA2, int nbuck, int e) {
    __shared__ int cur[256];
    int blk = blockIdx.x, tid = threadIdx.x;
    for (int k = tid; k < nbuck; k += 1024)
        cur[k] = tableT[(size_t)k * nA2 + blk * 4];
    __syncthreads();
    int base = blk * SCHUNK;
    if (base + SCHUNK <= e) {
        const int4* s4 = (const int4*)(src + base);
        const int4* d4 = (const int4*)(dst + base);
#pragma unroll
        for (int t = 0; t < SCHUNK / 4096; ++t) {
            int4 s = s4[t * 1024 + tid];
            int4 d = d4[t * 1024 + tid];
            int p0 = atomicAdd(&cur[d.x >> BBITS], 1); bed[p0] = make_int2(s.x, d.x);
            int p1 = atomicAdd(&cur[d.y >> BBITS], 1); bed[p1] = make_int2(s.y, d.y);
            int p2 = atomicAdd(&cur[d.z >> BBITS], 1); bed[p2] = make_int2(s.z, d.z);
            int p3 = atomicAdd(&cur[d.w >> BBITS], 1); bed[p3] = make_int2(s.w, d.w);
        }
    } else {
        for (int i = base + tid; i < e; i += 1024) {
            int d = dst[i];
            int p = atomicAdd(&cur[d >> BBITS], 1);
            bed[p] = make_int2(src[i], d);
        }
    }
}

// ---------------- K5: per-bucket rank/offsets/er/dinv (512 nodes/bucket, 1024 thr) --------
// er base for bucket b = bedStart[b] + 4096*b (pad slack <= 512*7 < 4096).
// offs2[node] = {start, end}; er stores BYTE offsets (src*256). dinv computed here.

__global__ __launch_bounds__(1024) void k_rank(const int2* __restrict__ bed,
                                               const int* __restrict__ tableT,
                                               int2* __restrict__ offs2,
                                               int* __restrict__ er,
                                               float* __restrict__ dinv,
                                               unsigned int* __restrict__ pad0,
                                               int nA2, int nbuck, int n, int e) {
    __shared__ int lcnt[512];
    __shared__ int loff[512];
    __shared__ int s[512];
    int tid = threadIdx.x, b = blockIdx.x;
    if (b == 0) {
        if (tid < 64) pad0[tid] = 0u;        // zero 256 B pad row of buf0
        if (tid == 0) dinv[n] = 0.f;         // dummy-row scale (layer-1 SRC_SCALE path)
    }
    if (tid < 512) lcnt[tid] = 0;
    __syncthreads();
    int start = tableT[(size_t)b * nA2];
    int end = (b + 1 < nbuck) ? tableT[(size_t)(b + 1) * nA2] : e;
    // pass 1: per-node counts (8 strided iterations)
    for (int i = start + tid; i < end; i += 1024)
        atomicAdd(&lcnt[bed[i].y & 511], 1);
    __syncthreads();
    int c = 0, p = 0, x = 0;
    if (tid < 512) {
        c = lcnt[tid];
        p = (c + 7) & ~7;
        x = p;
        s[tid] = x;
    }
    __syncthreads();
    for (int d = 1; d < 512; d <<= 1) {      // Hillis-Steele inclusive scan over 512
        int y = (tid < 512 && tid >= d) ? s[tid - d] : 0;
        __syncthreads();
        if (tid < 512) { x += y; s[tid] = x; }
        __syncthreads();
    }
    int ebase = start + (b << 12);
    if (tid < 512) {
        loff[tid] = x - p;
        int node = (b << BBITS) + tid;
        if (node < n) {
            int o = ebase + x - p;
            offs2[node] = make_int2(o, o + p);
            dinv[node] = rsqrtf((float)(c + 1));
            for (int j = c; j < p; ++j) er[o + j] = n << 8;   // dummy zero-row
        }
        lcnt[tid] = 0;                       // reuse as rank cursors (pass1 reads done)
    }
    __syncthreads();
    // pass 2: place (bed window L2-hot; er window dense full-line writebacks)
    for (int i = start + tid; i < end; i += 1024) {
        int2 q = bed[i];
        int l = q.y & 511;
        int r = atomicAdd(&lcnt[l], 1);
        er[ebase + loff[l] + r] = q.x << 8;  // BYTE offsets (src*256)
    }
}

// ---------------- fma_mix accumulate ----------------
// uint4 = 8 halfs: q.x -> f0,f1 | q.y -> f2,f3 | q.z -> f4,f5 | q.w -> f6,f7

__device__ __forceinline__ void acc_row4(float4& aL, float4& aH, uint4 q) {
    asm("v_fma_mix_f32 %0, %1, 1.0, %0 op_sel:[0,0,0] op_sel_hi:[1,0,0]" : "+v"(aL.x) : "v"(q.x));
    asm("v_fma_mix_f32 %0, %1, 1.0, %0 op_sel:[1,0,0] op_sel_hi:[1,0,0]" : "+v"(aL.y) : "v"(q.x));
    asm("v_fma_mix_f32 %0, %1, 1.0, %0 op_sel:[0,0,0] op_sel_hi:[1,0,0]" : "+v"(aL.z) : "v"(q.y));
    asm("v_fma_mix_f32 %0, %1, 1.0, %0 op_sel:[1,0,0] op_sel_hi:[1,0,0]" : "+v"(aL.w) : "v"(q.y));
    asm("v_fma_mix_f32 %0, %1, 1.0, %0 op_sel:[0,0,0] op_sel_hi:[1,0,0]" : "+v"(aH.x) : "v"(q.z));
    asm("v_fma_mix_f32 %0, %1, 1.0, %0 op_sel:[1,0,0] op_sel_hi:[1,0,0]" : "+v"(aH.y) : "v"(q.z));
    asm("v_fma_mix_f32 %0, %1, 1.0, %0 op_sel:[0,0,0] op_sel_hi:[1,0,0]" : "+v"(aH.z) : "v"(q.w));
    asm("v_fma_mix_f32 %0, %1, 1.0, %0 op_sel:[1,0,0] op_sel_hi:[1,0,0]" : "+v"(aH.w) : "v"(q.w));
}

__device__ __forceinline__ void acc_row4s(float4& aL, float4& aH, uint4 q, float s) {
    asm("v_fma_mix_f32 %0, %1, %2, %0 op_sel:[0,0,0] op_sel_hi:[1,0,0]" : "+v"(aL.x) : "v"(q.x), "v"(s));
    asm("v_fma_mix_f32 %0, %1, %2, %0 op_sel:[1,0,0] op_sel_hi:[1,0,0]" : "+v"(aL.y) : "v"(q.x), "v"(s));
    asm("v_fma_mix_f32 %0, %1, %2, %0 op_sel:[0,0,0] op_sel_hi:[1,0,0]" : "+v"(aL.z) : "v"(q.y), "v"(s));
    asm("v_fma_mix_f32 %0, %1, %2, %0 op_sel:[1,0,0] op_sel_hi:[1,0,0]" : "+v"(aL.w) : "v"(q.y), "v"(s));
    asm("v_fma_mix_f32 %0, %1, %2, %0 op_sel:[0,0,0] op_sel_hi:[1,0,0]" : "+v"(aH.x) : "v"(q.z), "v"(s));
    asm("v_fma_mix_f32 %0, %1, %2, %0 op_sel:[1,0,0] op_sel_hi:[1,0,0]" : "+v"(aH.y) : "v"(q.z), "v"(s));
    asm("v_fma_mix_f32 %0, %1, %2, %0 op_sel:[0,0,0] op_sel_hi:[1,0,0]" : "+v"(aH.z) : "v"(q.w), "v"(s));
    asm("v_fma_mix_f32 %0, %1, %2, %0 op_sel:[1,0,0] op_sel_hi:[1,0,0]" : "+v"(aH.w) : "v"(q.w), "v"(s));
}

// ---------------- CSR aggregation + bias + ReLU + BN (+ optional classifier) ----------------
// 16 lanes/node, uint4 gathers, er SOFTWARE PREFETCH: next iteration's er pair is loaded
// while this iteration's gathers are in flight (removes er->gather serial hop per iter).

template <bool FUSE_CLS, bool SRC_SCALE>
__global__ __launch_bounds__(256) void k_aggregate(const uint4* __restrict__ Ah,
                                                   const int2* __restrict__ offs2,
                                                   const int* __restrict__ er,
                                                   const float* __restrict__ dinv,
                                                   const float* __restrict__ bias,
                                                   const float* __restrict__ g,
                                                   const float* __restrict__ be,
                                                   const float* __restrict__ rm,
                                                   const float* __restrict__ rv,
                                                   uint4* __restrict__ Hout,
                                                   const float* __restrict__ Wc,
                                                   const float* __restrict__ bc,
                                                   float* __restrict__ out, int n) {
    int lane = threadIdx.x & 15;
    int node = blockIdx.x * 16 + (threadIdx.x >> 4);
    if (node >= n) return;

    const char* AhB = (const char*)Ah;
    unsigned int l16b = (unsigned int)lane * 16u;

    float di = dinv[node];
    float4 aL = f4zero(), aH = f4zero();
    {
        uint4 qs = *(const uint4*)(AhB + (((unsigned int)node << 8) + l16b));
        if (SRC_SCALE) acc_row4s(aL, aH, qs, di);
        else           acc_row4(aL, aH, qs);
    }

    int2 offc = offs2[node];
    int e0 = offc.x, e1 = offc.y;
    int4 ra = make_int4(0, 0, 0, 0), rb = make_int4(0, 0, 0, 0);
    if (e0 < e1) {
        ra = *(const int4*)(er + e0);
        rb = *(const int4*)(er + e0 + 4);
    }
    for (int ee = e0; ee < e1; ee += 8) {
        int4 ran = ra, rbn = rb;
        if (ee + 8 < e1) {                   // prefetch next er pair (latency hidden)
            ran = *(const int4*)(er + ee + 8);
            rbn = *(const int4*)(er + ee + 12);
        }
        uint4 v0 = *(const uint4*)(AhB + ((unsigned int)ra.x + l16b));
        uint4 v1 = *(const uint4*)(AhB + ((unsigned int)ra.y + l16b));
        uint4 v2 = *(const uint4*)(AhB + ((unsigned int)ra.z + l16b));
        uint4 v3 = *(const uint4*)(AhB + ((unsigned int)ra.w + l16b));
        uint4 v4 = *(const uint4*)(AhB + ((unsigned int)rb.x + l16b));
        uint4 v5 = *(const uint4*)(AhB + ((unsigned int)rb.y + l16b));
        uint4 v6 = *(const uint4*)(AhB + ((unsigned int)rb.z + l16b));
        uint4 v7 = *(const uint4*)(AhB + ((unsigned int)rb.w + l16b));
        if (SRC_SCALE) {
            float d0 = dinv[(unsigned int)ra.x >> 8];
            float d1 = dinv[(unsigned int)ra.y >> 8];
            float d2 = dinv[(unsigned int)ra.z >> 8];
            float d3 = dinv[(unsigned int)ra.w >> 8];
            float d4 = dinv[(unsigned int)rb.x >> 8];
            float d5 = dinv[(unsigned int)rb.y >> 8];
            float d6 = dinv[(unsigned int)rb.z >> 8];
            float d7 = dinv[(unsigned int)rb.w >> 8];
            acc_row4s(aL, aH, v0, d0); acc_row4s(aL, aH, v1, d1);
            acc_row4s(aL, aH, v2, d2); acc_row4s(aL, aH, v3, d3);
            acc_row4s(aL, aH, v4, d4); acc_row4s(aL, aH, v5, d5);
            acc_row4s(aL, aH, v6, d6); acc_row4s(aL, aH, v7, d7);
        } else {
            acc_row4(aL, aH, v0); acc_row4(aL, aH, v1); acc_row4(aL, aH, v2); acc_row4(aL, aH, v3);
            acc_row4(aL, aH, v4); acc_row4(aL, aH, v5); acc_row4(aL, aH, v6); acc_row4(aL, aH, v7);
        }
        ra = ran; rb = rbn;
    }

    aL.x *= di; aL.y *= di; aL.z *= di; aL.w *= di;
    aH.x *= di; aH.y *= di; aH.z *= di; aH.w *= di;

    // lane covers features [8*lane, 8*lane+8) -> float4 indices 2*lane, 2*lane+1
    float4 bL  = ((const float4*)bias)[2 * lane], bH  = ((const float4*)bias)[2 * lane + 1];
    float4 gL  = ((const float4*)g)[2 * lane],    gH  = ((const float4*)g)[2 * lane + 1];
    float4 beL = ((const float4*)be)[2 * lane],   beH = ((const float4*)be)[2 * lane + 1];
    float4 rmL = ((const float4*)rm)[2 * lane],   rmH = ((const float4*)rm)[2 * lane + 1];
    float4 rvL = ((const float4*)rv)[2 * lane],   rvH = ((const float4*)rv)[2 * lane + 1];

    float4 oL, oH;
    float v;
    v = fmaxf(aL.x + bL.x, 0.f); oL.x = (v - rmL.x) * rsqrtf(rvL.x + BN_EPS) * gL.x + beL.x;
    v = fmaxf(aL.y + bL.y, 0.f); oL.y = (v - rmL.y) * rsqrtf(rvL.y + BN_EPS) * gL.y + beL.y;
    v = fmaxf(aL.z + bL.z, 0.f); oL.z = (v - rmL.z) * rsqrtf(rvL.z + BN_EPS) * gL.z + beL.z;
    v = fmaxf(aL.w + bL.w, 0.f); oL.w = (v - rmL.w) * rsqrtf(rvL.w + BN_EPS) * gL.w + beL.w;
    v = fmaxf(aH.x + bH.x, 0.f); oH.x = (v - rmH.x) * rsqrtf(rvH.x + BN_EPS) * gH.x + beH.x;
    v = fmaxf(aH.y + bH.y, 0.f); oH.y = (v - rmH.y) * rsqrtf(rvH.y + BN_EPS) * gH.y + beH.y;
    v = fmaxf(aH.z + bH.z, 0.f); oH.z = (v - rmH.z) * rsqrtf(rvH.z + BN_EPS) * gH.z + beH.z;
    v = fmaxf(aH.w + bH.w, 0.f); oH.w = (v - rmH.w) * rsqrtf(rvH.w + BN_EPS) * gH.w + beH.w;

    if (!FUSE_CLS) {
        __half2 p0 = __floats2half2_rn(oL.x, oL.y);
        __half2 p1 = __floats2half2_rn(oL.z, oL.w);
        __half2 p2 = __floats2half2_rn(oH.x, oH.y);
        __half2 p3 = __floats2half2_rn(oH.z, oH.w);
        uint4 u;
        u.x = *(unsigned int*)&p0;
        u.y = *(unsigned int*)&p1;
        u.z = *(unsigned int*)&p2;
        u.w = *(unsigned int*)&p3;
        Hout[(size_t)node * 16 + lane] = u;
    } else {
        const float4* Wv = (const float4*)Wc;   // Wc[f][2]: float4 i = features 2i,2i+1
        float4 w0 = Wv[4 * lane];
        float4 w1 = Wv[4 * lane + 1];
        float4 w2 = Wv[4 * lane + 2];
        float4 w3 = Wv[4 * lane + 3];
        float p0 = oL.x * w0.x + oL.y * w0.z + oL.z * w1.x + oL.w * w1.z
                 + oH.x * w2.x + oH.y * w2.z + oH.z * w3.x + oH.w * w3.z;
        float p1 = oL.x * w0.y + oL.y * w0.w + oL.z * w1.y + oL.w * w1.w
                 + oH.x * w2.y + oH.y * w2.w + oH.z * w3.y + oH.w * w3.w;
#pragma unroll
        for (int d = 8; d >= 1; d >>= 1) {
            p0 += __shfl_down(p0, d, 16);
            p1 += __shfl_down(p1, d, 16);
        }
        if (lane == 0) {
            out[node * 2 + 0] = p0 + bc[0];
            out[node * 2 + 1] = p1 + bc[1];
        }
    }
}

// ---------------- layer-2/3 GEMM (packed W, dinv epilogue) ----------------

__global__ __launch_bounds__(256) void k_gemm_mfma(const void* __restrict__ Av,
                                                   const _Float16* __restrict__ pW,
                                                   const float* __restrict__ dinv,
                                                   uint4* __restrict__ C, int n) {
    __shared__ char smem[32768];
    gemm_body<false, false, true>(blockIdx.x, threadIdx.x, smem, Av, pW, dinv, C, n);
}

// ---------------- launch ----------------

extern "C" void kernel_launch(void* const* d_in, const int* in_sizes, int n_in,
                              void* d_out, int out_size, void* d_ws, size_t ws_size,
                              hipStream_t stream) {
    const float* x   = (const float*)d_in[0];
    const int*   ei  = (const int*)d_in[1];
    const float* W1  = (const float*)d_in[2];
    const float* b1  = (const float*)d_in[3];
    const float* W2  = (const float*)d_in[4];
    const float* b2  = (const float*)d_in[5];
    const float* W3  = (const float*)d_in[6];
    const float* b3  = (const float*)d_in[7];
    const float* g1  = (const float*)d_in[8];
    const float* be1 = (const float*)d_in[9];
    const float* rm1 = (const float*)d_in[10];
    const float* rv1 = (const float*)d_in[11];
    const float* g2  = (const float*)d_in[12];
    const float* be2 = (const float*)d_in[13];
    const float* rm2 = (const float*)d_in[14];
    const float* rv2 = (const float*)d_in[15];
    const float* g3  = (const float*)d_in[16];
    const float* be3 = (const float*)d_in[17];
    const float* rm3 = (const float*)d_in[18];
    const float* rv3 = (const float*)d_in[19];
    const float* Wc  = (const float*)d_in[20];
    const float* bc  = (const float*)d_in[21];
    float* out = (float*)d_out;

    int n = in_sizes[0] / 128;
    int e = in_sizes[1] / 2;
    const int* src = ei;
    const int* dst = ei + e;

    char* ws = (char*)d_ws;
    size_t off = 0;
    auto alloc = [&](size_t bytes) -> char* {
        char* p = ws + off;
        off += (bytes + 255) & ~(size_t)255;
        return p;
    };
    int nA2   = (e + HCHUNK - 1) / HCHUNK;          // hist chunks (2048)
    int nS    = (e + SCHUNK - 1) / SCHUNK;          // scatter blocks (8192)
    int nbuck = (n + (1 << BBITS) - 1) >> BBITS;
    int tlen  = nbuck * nA2;
    int erCap = e + (nbuck << 12) + 64;

    char*      buf0     = (char*) alloc((size_t)(n + 1) * 256);   // gemm out (ping)
    char*      buf1     = (char*) alloc((size_t)(n + 1) * 256);   // agg out (pong); bed aliases
    float*     dinv     = (float*)alloc((size_t)(n + 1) * 4);
    int2*      offs2    = (int2*) alloc((size_t)n * 8);
    int*       tableT   = (int*)  alloc((size_t)(tlen + 1) * 4);
    int*       parts    = (int*)  alloc(8192);
    int*       er       = (int*)  alloc((size_t)erCap * 4);
    _Float16*  pW       = (_Float16*)alloc(3 * 16384 * 2);        // W2 at +16384, W3 at +32768
    (void)ws_size; (void)n_in; (void)out_size;

    // bed aliases buf1 (dead until agg1 writes; consumed by k_rank)
    int2* bed = (int2*)buf1;                         // e*8 = 12.8 MB < 25.6 MB

    int nbT   = (tlen + 1023) / 1024;
    int gT    = (tlen + 255) / 256;
    int gGemm = (n + 63) / 64;
    int gAgg  = (n + 15) / 16;

    // hist (782) ∥ layer-1 GEMM self-packing W1 (1563) ∥ pack W2/W3 (16)
    k_hist_gemm1<<<nA2 + gGemm + 16, 256, 0, stream>>>(
        dst, tableT, nA2, nbuck, e, x, W1, W2, W3, pW, (uint4*)buf0, n, gGemm);
    k_scan_block<<<nbT, 1024, 0, stream>>>(tableT, tableT, parts, tlen);
    k_scan_addp<<<gT, 256, 0, stream>>>(tableT, parts, tlen);
    k_scatter<<<nS, 1024, 0, stream>>>(src, dst, tableT, bed, nA2, nbuck, e);
    k_rank<<<nbuck, 1024, 0, stream>>>(bed, tableT, offs2, er, dinv,
                                       (unsigned int*)(buf0 + (size_t)n * 256),
                                       nA2, nbuck, n, e);

    // layer 1: agg (buf0 unscaled -> buf1, SRC_SCALE)
    k_aggregate<false, true><<<gAgg, 256, 0, stream>>>(
        (const uint4*)buf0, offs2, er, dinv, b1, g1, be1, rm1, rv1,
        (uint4*)buf1, nullptr, nullptr, nullptr, n);
    // layer 2: gemm (buf1 -> buf0, ×dinv), agg (buf0 -> buf1)
    k_gemm_mfma<<<gGemm, 256, 0, stream>>>(buf1, pW + 16384, dinv, (uint4*)buf0, n);
    k_aggregate<false, false><<<gAgg, 256, 0, stream>>>(
        (const uint4*)buf0, offs2, er, dinv, b2, g2, be2, rm2, rv2,
        (uint4*)buf1, nullptr, nullptr, nullptr, n);
    // layer 3: gemm (buf1 -> buf0, ×dinv), agg + classifier (buf0 -> out)
    k_gemm_mfma<<<gGemm, 256, 0, stream>>>(buf1, pW + 32768, dinv, (uint4*)buf0, n);
    k_aggregate<true, false><<<gAgg, 256, 0, stream>>>(
        (const uint4*)buf0, offs2, er, dinv, b3, g3, be3, rm3, rv3,
        nullptr, Wc, bc, out, n);
}

// Round 11
// 371.702 us; speedup vs baseline: 1.0451x; 1.0451x over previous
//
#include <hip/hip_runtime.h>
#include <hip/hip_fp16.h>

#define BN_EPS 1e-5f
#define CHUNK 8192            // edges per bucketing block (hist and scatter must match)
#define BBITS 9               // 512 nodes per bucket

typedef _Float16 half8 __attribute__((ext_vector_type(8)));
typedef float f32x4 __attribute__((ext_vector_type(4)));

__device__ __forceinline__ float4 f4zero() { return make_float4(0.f, 0.f, 0.f, 0.f); }

// ---------------- K1: packW(all 3) + bucket histogram (LDS atomics, 1024 thr) ----------------

__global__ __launch_bounds__(1024) void k_pack_hist(const float* __restrict__ W1,
                                                    const float* __restrict__ W2,
                                                    const float* __restrict__ W3,
                                                    _Float16* __restrict__ pW,
                                                    const int* __restrict__ dst,
                                                    int* __restrict__ tableT,
                                                    int nA, int nbuck, int e) {
    __shared__ int h[256];
    int tid = threadIdx.x;
    if (blockIdx.x < 6) {             // W pre-pack: f32 [128][128] -> f16 B-fragment order
        int t = blockIdx.x * 1024 + tid;  // 0..6143
        int wi = t >> 11;
        int tt = t & 2047;
        const float* W = (wi == 0) ? W1 : ((wi == 1) ? W2 : W3);
        int kc = tt >> 9;
        int rem = tt & 511;
        int ct = rem >> 6;
        int lane = rem & 63;
        int q = lane >> 4;
        int col = ct * 16 + (lane & 15);
        half8 hh;
#pragma unroll
        for (int j = 0; j < 8; ++j)
            hh[j] = (_Float16)W[(kc * 32 + q * 8 + j) * 128 + col];
        *(half8*)(pW + (size_t)t * 8) = hh;
        return;
    }
    int blk = blockIdx.x - 6;
    if (tid < 256) h[tid] = 0;
    __syncthreads();
    int base = blk * CHUNK;
    if (base + CHUNK <= e) {
        const int4* d4 = (const int4*)(dst + base);
#pragma unroll
        for (int t = 0; t < CHUNK / 4096; ++t) {
            int4 d = d4[t * 1024 + tid];
            atomicAdd(&h[d.x >> BBITS], 1);
            atomicAdd(&h[d.y >> BBITS], 1);
            atomicAdd(&h[d.z >> BBITS], 1);
            atomicAdd(&h[d.w >> BBITS], 1);
        }
    } else {
        for (int i = base + tid; i < e; i += 1024)
            atomicAdd(&h[dst[i] >> BBITS], 1);
    }
    __syncthreads();
    for (int k = tid; k < nbuck; k += 1024)
        tableT[(size_t)k * nA + blk] = h[k];
}

// ---------------- K2/K3: 2-op exclusive scan of tableT ----------------

__global__ __launch_bounds__(1024) void k_scan_block(const int* __restrict__ in,
                                                     int* __restrict__ outp,
                                                     int* __restrict__ partials, int len) {
    __shared__ int s[1024];
    int t = threadIdx.x;
    int gid = blockIdx.x * 1024 + t;
    int v = (gid < len) ? in[gid] : 0;
    int x = v;
    s[t] = x;
    __syncthreads();
    for (int d = 1; d < 1024; d <<= 1) {
        int y = (t >= d) ? s[t - d] : 0;
        __syncthreads();
        x += y;
        s[t] = x;
        __syncthreads();
    }
    if (gid < len) outp[gid] = x - v;
    if (t == 1023) partials[blockIdx.x] = x;
}

__global__ __launch_bounds__(256) void k_scan_addp(int* __restrict__ data,
                                                   const int* __restrict__ partials, int len) {
    __shared__ int red[256];
    int tid = threadIdx.x;
    int K = blockIdx.x >> 2;          // number of preceding 1024-segments
    int s = 0;
    for (int t = tid; t < K; t += 256) s += partials[t];
    red[tid] = s;
    __syncthreads();
    for (int d = 128; d > 0; d >>= 1) {
        if (tid < d) red[tid] += red[tid + d];
        __syncthreads();
    }
    int gid = blockIdx.x * 256 + tid;
    if (gid < len) data[gid] += red[0];
}

// ---------------- K4: bucket-grouped COO scatter (LDS cursors, 1024 thr) ----------------
// 512-node buckets: per-block bucket runs ~42 edges (~336 B) -> minimal line amplification.

__global__ __launch_bounds__(1024) void k_scatter(const int* __restrict__ src,
                                                  const int* __restrict__ dst,
                                                  const int* __restrict__ tableT,
                                                  int2* __restrict__ bed,
                                                  int nA, int nbuck, int e) {
    __shared__ int cur[256];
    int blk = blockIdx.x, tid = threadIdx.x;
    for (int k = tid; k < nbuck; k += 1024)
        cur[k] = tableT[(size_t)k * nA + blk];
    __syncthreads();
    int base = blk * CHUNK;
    if (base + CHUNK <= e) {
        const int4* s4 = (const int4*)(src + base);
        const int4* d4 = (const int4*)(dst + base);
#pragma unroll
        for (int t = 0; t < CHUNK / 4096; ++t) {
            int4 s = s4[t * 1024 + tid];
            int4 d = d4[t * 1024 + tid];
            int p0 = atomicAdd(&cur[d.x >> BBITS], 1); bed[p0] = make_int2(s.x, d.x);
            int p1 = atomicAdd(&cur[d.y >> BBITS], 1); bed[p1] = make_int2(s.y, d.y);
            int p2 = atomicAdd(&cur[d.z >> BBITS], 1); bed[p2] = make_int2(s.z, d.z);
            int p3 = atomicAdd(&cur[d.w >> BBITS], 1); bed[p3] = make_int2(s.w, d.w);
        }
    } else {
        for (int i = base + tid; i < e; i += 1024) {
            int d = dst[i];
            int p = atomicAdd(&cur[d >> BBITS], 1);
            bed[p] = make_int2(src[i], d);
        }
    }
}

// ---------------- GEMM body: C[n,128](f16) = (A @ W) [* dinv[row] if SCALE] ----------------

template <bool AF32, bool SCALE>
__device__ __forceinline__ void gemm_body(int bid, int tid, char* smem,
                                          const void* __restrict__ Av,
                                          const _Float16* __restrict__ pW,
                                          const float* __restrict__ dinv,
                                          uint4* __restrict__ C, int n) {
    uint4* sW = (uint4*)smem;
    {
        const uint4* gW = (const uint4*)pW;
#pragma unroll
        for (int i = 0; i < 8; ++i) sW[tid + 256 * i] = gW[tid + 256 * i];
    }
    __syncthreads();

    int wave = tid >> 6, lane = tid & 63;
    int quad = lane >> 4, l16 = lane & 15;
    int row0 = bid * 64 + wave * 16;
    int arow = row0 + l16;
    int arowc = (arow < n) ? arow : (n - 1);

    half8 af[4];
    if (AF32) {
        const float* A = (const float*)Av + (size_t)arowc * 128 + quad * 8;
#pragma unroll
        for (int kc = 0; kc < 4; ++kc) {
            float4 lo = *(const float4*)(A + kc * 32);
            float4 hi = *(const float4*)(A + kc * 32 + 4);
            half8 h;
            h[0] = (_Float16)lo.x; h[1] = (_Float16)lo.y;
            h[2] = (_Float16)lo.z; h[3] = (_Float16)lo.w;
            h[4] = (_Float16)hi.x; h[5] = (_Float16)hi.y;
            h[6] = (_Float16)hi.z; h[7] = (_Float16)hi.w;
            af[kc] = h;
        }
    } else {
        const _Float16* A = (const _Float16*)Av + (size_t)arowc * 128 + quad * 8;
#pragma unroll
        for (int kc = 0; kc < 4; ++kc)
            af[kc] = *(const half8*)(A + kc * 32);
    }

    f32x4 acc[8];
#pragma unroll
    for (int ct = 0; ct < 8; ++ct) acc[ct] = (f32x4){0.f, 0.f, 0.f, 0.f};

#pragma unroll
    for (int kc = 0; kc < 4; ++kc) {
#pragma unroll
        for (int ct = 0; ct < 8; ++ct) {
            half8 bf = *(half8*)&sW[(kc * 8 + ct) * 64 + lane];
            acc[ct] = __builtin_amdgcn_mfma_f32_16x16x32_f16(af[kc], bf, acc[ct], 0, 0, 0);
        }
    }

    __syncthreads();

    _Float16* eb = (_Float16*)smem + wave * 16 * 136;   // 136 halfs = 272 B row stride
    float dv[4];
#pragma unroll
    for (int r = 0; r < 4; ++r) {
        if (SCALE) {
            int rr = row0 + quad * 4 + r;
            dv[r] = dinv[(rr < n) ? rr : (n - 1)];
        } else dv[r] = 1.f;
    }
#pragma unroll
    for (int ct = 0; ct < 8; ++ct)
#pragma unroll
        for (int r = 0; r < 4; ++r)
            eb[(quad * 4 + r) * 136 + ct * 16 + l16] =
                (_Float16)(SCALE ? acc[ct][r] * dv[r] : acc[ct][r]);

#pragma unroll
    for (int i = 0; i < 4; ++i) {
        int linear = i * 64 + lane;
        int r = linear >> 4, c = linear & 15;
        uint4 v = *(uint4*)((char*)eb + r * 272 + c * 16);
        int row = row0 + r;
        if (row < n) C[(size_t)row * 16 + c] = v;
    }
}

__global__ __launch_bounds__(256) void k_gemm_mfma(const void* __restrict__ Av,
                                                   const _Float16* __restrict__ pW,
                                                   const float* __restrict__ dinv,
                                                   uint4* __restrict__ C, int n) {
    __shared__ char smem[32768];
    gemm_body<false, true>(blockIdx.x, threadIdx.x, smem, Av, pW, dinv, C, n);
}

// ---------------- K5: per-bucket rank/offsets/er/dinv (512 nodes/bucket) ∥ GEMM1 ----------
// er base for bucket b = bedStart[b] + 4096*b (pad slack <= 512*7 < 4096).
// offs2[node] = {start, end}; er stores BYTE offsets (src*256). dinv computed here.

__global__ __launch_bounds__(256) void k_rank_gemm1(const int2* __restrict__ bed,
                                                    const int* __restrict__ tableT,
                                                    int2* __restrict__ offs2,
                                                    int* __restrict__ er,
                                                    float* __restrict__ dinv,
                                                    unsigned int* __restrict__ pad0,
                                                    const float* __restrict__ x,
                                                    const _Float16* __restrict__ pW,
                                                    uint4* __restrict__ C,
                                                    int nA, int nbuck, int n, int e) {
    __shared__ char smem[32768];
    int tid = threadIdx.x;
    int b = blockIdx.x;
    if (b >= nbuck) {                        // layer-1 GEMM from f32 x (dinv-free, unscaled)
        gemm_body<true, false>(b - nbuck, tid, smem, x, pW, nullptr, C, n);
        return;
    }
    int* lcnt = (int*)smem;                  // [512]
    int* loff = lcnt + 512;                  // [512]
    int* s    = loff + 512;                  // [256]
    if (b == 0) {
        if (tid < 64) pad0[tid] = 0u;        // zero 256 B pad row of buf0
        if (tid == 0) dinv[n] = 0.f;         // dummy-row scale (layer-1 SRC_SCALE path)
    }
    for (int k = tid; k < 512; k += 256) lcnt[k] = 0;
    __syncthreads();
    int start = tableT[(size_t)b * nA];
    int end = (b + 1 < nbuck) ? tableT[(size_t)(b + 1) * nA] : e;
    // pass 1: per-node counts
    for (int i = start + tid; i < end; i += 256)
        atomicAdd(&lcnt[bed[i].y & 511], 1);
    __syncthreads();
    // padded scan over 512 entries, 2 per thread
    int t2 = tid * 2;
    int c0 = lcnt[t2], c1 = lcnt[t2 + 1];
    int p0 = (c0 + 7) & ~7, p1 = (c1 + 7) & ~7;
    int xsum = p0 + p1;
    s[tid] = xsum;
    __syncthreads();
    for (int d = 1; d < 256; d <<= 1) {
        int y = (tid >= d) ? s[tid - d] : 0;
        __syncthreads();
        xsum += y;
        s[tid] = xsum;
        __syncthreads();
    }
    int ebase = start + (b << 12);
    int base0 = xsum - p0 - p1;              // exclusive padded offset of node t2
    loff[t2] = base0;
    loff[t2 + 1] = base0 + p0;
    {
        int node = (b << BBITS) + t2;
        if (node < n) {
            int o = ebase + base0;
            offs2[node] = make_int2(o, o + p0);
            dinv[node] = rsqrtf((float)(c0 + 1));
            for (int j = c0; j < p0; ++j) er[o + j] = n << 8;   // dummy zero-row
        }
        node = (b << BBITS) + t2 + 1;
        if (node < n) {
            int o = ebase + base0 + p0;
            offs2[node] = make_int2(o, o + p1);
            dinv[node] = rsqrtf((float)(c1 + 1));
            for (int j = c1; j < p1; ++j) er[o + j] = n << 8;
        }
    }
    __syncthreads();
    for (int k = tid; k < 512; k += 256) lcnt[k] = 0;   // reuse as rank cursors
    __syncthreads();
    // pass 2: place (bed window is L2-hot; er window ~fits L2 -> full-line writebacks)
    for (int i = start + tid; i < end; i += 256) {
        int2 q = bed[i];
        int l = q.y & 511;
        int r = atomicAdd(&lcnt[l], 1);
        er[ebase + loff[l] + r] = q.x << 8;             // BYTE offsets (src*256)
    }
}

// ---------------- fma_mix accumulate ----------------
// uint4 = 8 halfs: q.x -> f0,f1 | q.y -> f2,f3 | q.z -> f4,f5 | q.w -> f6,f7

__device__ __forceinline__ void acc_row4(float4& aL, float4& aH, uint4 q) {
    asm("v_fma_mix_f32 %0, %1, 1.0, %0 op_sel:[0,0,0] op_sel_hi:[1,0,0]" : "+v"(aL.x) : "v"(q.x));
    asm("v_fma_mix_f32 %0, %1, 1.0, %0 op_sel:[1,0,0] op_sel_hi:[1,0,0]" : "+v"(aL.y) : "v"(q.x));
    asm("v_fma_mix_f32 %0, %1, 1.0, %0 op_sel:[0,0,0] op_sel_hi:[1,0,0]" : "+v"(aL.z) : "v"(q.y));
    asm("v_fma_mix_f32 %0, %1, 1.0, %0 op_sel:[1,0,0] op_sel_hi:[1,0,0]" : "+v"(aL.w) : "v"(q.y));
    asm("v_fma_mix_f32 %0, %1, 1.0, %0 op_sel:[0,0,0] op_sel_hi:[1,0,0]" : "+v"(aH.x) : "v"(q.z));
    asm("v_fma_mix_f32 %0, %1, 1.0, %0 op_sel:[1,0,0] op_sel_hi:[1,0,0]" : "+v"(aH.y) : "v"(q.z));
    asm("v_fma_mix_f32 %0, %1, 1.0, %0 op_sel:[0,0,0] op_sel_hi:[1,0,0]" : "+v"(aH.z) : "v"(q.w));
    asm("v_fma_mix_f32 %0, %1, 1.0, %0 op_sel:[1,0,0] op_sel_hi:[1,0,0]" : "+v"(aH.w) : "v"(q.w));
}

__device__ __forceinline__ void acc_row4s(float4& aL, float4& aH, uint4 q, float s) {
    asm("v_fma_mix_f32 %0, %1, %2, %0 op_sel:[0,0,0] op_sel_hi:[1,0,0]" : "+v"(aL.x) : "v"(q.x), "v"(s));
    asm("v_fma_mix_f32 %0, %1, %2, %0 op_sel:[1,0,0] op_sel_hi:[1,0,0]" : "+v"(aL.y) : "v"(q.x), "v"(s));
    asm("v_fma_mix_f32 %0, %1, %2, %0 op_sel:[0,0,0] op_sel_hi:[1,0,0]" : "+v"(aL.z) : "v"(q.y), "v"(s));
    asm("v_fma_mix_f32 %0, %1, %2, %0 op_sel:[1,0,0] op_sel_hi:[1,0,0]" : "+v"(aL.w) : "v"(q.y), "v"(s));
    asm("v_fma_mix_f32 %0, %1, %2, %0 op_sel:[0,0,0] op_sel_hi:[1,0,0]" : "+v"(aH.x) : "v"(q.z), "v"(s));
    asm("v_fma_mix_f32 %0, %1, %2, %0 op_sel:[1,0,0] op_sel_hi:[1,0,0]" : "+v"(aH.y) : "v"(q.z), "v"(s));
    asm("v_fma_mix_f32 %0, %1, %2, %0 op_sel:[0,0,0] op_sel_hi:[1,0,0]" : "+v"(aH.z) : "v"(q.w), "v"(s));
    asm("v_fma_mix_f32 %0, %1, %2, %0 op_sel:[1,0,0] op_sel_hi:[1,0,0]" : "+v"(aH.w) : "v"(q.w), "v"(s));
}

// ---------------- CSR aggregation + bias + ReLU + BN (+ optional classifier) ----------------
// 16 lanes/node, uint4 gathers (R5-verified shape: VGPR 32, occ ~67% for plain path —
// dinv[node] loaded AFTER the loop when not needed earlier). SRC_SCALE: source rows
// unscaled; multiply dinv[src] in fma_mix (layer 1 only).

template <bool FUSE_CLS, bool SRC_SCALE>
__global__ __launch_bounds__(256) void k_aggregate(const uint4* __restrict__ Ah,
                                                   const int2* __restrict__ offs2,
                                                   const int* __restrict__ er,
                                                   const float* __restrict__ dinv,
                                                   const float* __restrict__ bias,
                                                   const float* __restrict__ g,
                                                   const float* __restrict__ be,
                                                   const float* __restrict__ rm,
                                                   const float* __restrict__ rv,
                                                   uint4* __restrict__ Hout,
                                                   const float* __restrict__ Wc,
                                                   const float* __restrict__ bc,
                                                   float* __restrict__ out, int n) {
    int lane = threadIdx.x & 15;
    int node = blockIdx.x * 16 + (threadIdx.x >> 4);
    if (node >= n) return;

    const char* AhB = (const char*)Ah;
    unsigned int l16b = (unsigned int)lane * 16u;

    float di = 0.f;
    if (SRC_SCALE) di = dinv[node];          // needed for self-loop scale
    float4 aL = f4zero(), aH = f4zero();
    {
        uint4 qs = *(const uint4*)(AhB + (((unsigned int)node << 8) + l16b));
        if (SRC_SCALE) acc_row4s(aL, aH, qs, di);
        else           acc_row4(aL, aH, qs);
    }

    int2 offc = offs2[node];
    for (int e = offc.x; e < offc.y; e += 8) {
        int4 ra = *(const int4*)(er + e);
        int4 rb = *(const int4*)(er + e + 4);
        uint4 v0 = *(const uint4*)(AhB + ((unsigned int)ra.x + l16b));
        uint4 v1 = *(const uint4*)(AhB + ((unsigned int)ra.y + l16b));
        uint4 v2 = *(const uint4*)(AhB + ((unsigned int)ra.z + l16b));
        uint4 v3 = *(const uint4*)(AhB + ((unsigned int)ra.w + l16b));
        uint4 v4 = *(const uint4*)(AhB + ((unsigned int)rb.x + l16b));
        uint4 v5 = *(const uint4*)(AhB + ((unsigned int)rb.y + l16b));
        uint4 v6 = *(const uint4*)(AhB + ((unsigned int)rb.z + l16b));
        uint4 v7 = *(const uint4*)(AhB + ((unsigned int)rb.w + l16b));
        if (SRC_SCALE) {
            float d0 = dinv[(unsigned int)ra.x >> 8];
            float d1 = dinv[(unsigned int)ra.y >> 8];
            float d2 = dinv[(unsigned int)ra.z >> 8];
            float d3 = dinv[(unsigned int)ra.w >> 8];
            float d4 = dinv[(unsigned int)rb.x >> 8];
            float d5 = dinv[(unsigned int)rb.y >> 8];
            float d6 = dinv[(unsigned int)rb.z >> 8];
            float d7 = dinv[(unsigned int)rb.w >> 8];
            acc_row4s(aL, aH, v0, d0); acc_row4s(aL, aH, v1, d1);
            acc_row4s(aL, aH, v2, d2); acc_row4s(aL, aH, v3, d3);
            acc_row4s(aL, aH, v4, d4); acc_row4s(aL, aH, v5, d5);
            acc_row4s(aL, aH, v6, d6); acc_row4s(aL, aH, v7, d7);
        } else {
            acc_row4(aL, aH, v0); acc_row4(aL, aH, v1); acc_row4(aL, aH, v2); acc_row4(aL, aH, v3);
            acc_row4(aL, aH, v4); acc_row4(aL, aH, v5); acc_row4(aL, aH, v6); acc_row4(aL, aH, v7);
        }
    }

    if (!SRC_SCALE) di = dinv[node];         // R5 placement: load after the gather loop
    aL.x *= di; aL.y *= di; aL.z *= di; aL.w *= di;
    aH.x *= di; aH.y *= di; aH.z *= di; aH.w *= di;

    // lane covers features [8*lane, 8*lane+8) -> float4 indices 2*lane, 2*lane+1
    float4 bL  = ((const float4*)bias)[2 * lane], bH  = ((const float4*)bias)[2 * lane + 1];
    float4 gL  = ((const float4*)g)[2 * lane],    gH  = ((const float4*)g)[2 * lane + 1];
    float4 beL = ((const float4*)be)[2 * lane],   beH = ((const float4*)be)[2 * lane + 1];
    float4 rmL = ((const float4*)rm)[2 * lane],   rmH = ((const float4*)rm)[2 * lane + 1];
    float4 rvL = ((const float4*)rv)[2 * lane],   rvH = ((const float4*)rv)[2 * lane + 1];

    float4 oL, oH;
    float v;
    v = fmaxf(aL.x + bL.x, 0.f); oL.x = (v - rmL.x) * rsqrtf(rvL.x + BN_EPS) * gL.x + beL.x;
    v = fmaxf(aL.y + bL.y, 0.f); oL.y = (v - rmL.y) * rsqrtf(rvL.y + BN_EPS) * gL.y + beL.y;
    v = fmaxf(aL.z + bL.z, 0.f); oL.z = (v - rmL.z) * rsqrtf(rvL.z + BN_EPS) * gL.z + beL.z;
    v = fmaxf(aL.w + bL.w, 0.f); oL.w = (v - rmL.w) * rsqrtf(rvL.w + BN_EPS) * gL.w + beL.w;
    v = fmaxf(aH.x + bH.x, 0.f); oH.x = (v - rmH.x) * rsqrtf(rvH.x + BN_EPS) * gH.x + beH.x;
    v = fmaxf(aH.y + bH.y, 0.f); oH.y = (v - rmH.y) * rsqrtf(rvH.y + BN_EPS) * gH.y + beH.y;
    v = fmaxf(aH.z + bH.z, 0.f); oH.z = (v - rmH.z) * rsqrtf(rvH.z + BN_EPS) * gH.z + beH.z;
    v = fmaxf(aH.w + bH.w, 0.f); oH.w = (v - rmH.w) * rsqrtf(rvH.w + BN_EPS) * gH.w + beH.w;

    if (!FUSE_CLS) {
        __half2 p0 = __floats2half2_rn(oL.x, oL.y);
        __half2 p1 = __floats2half2_rn(oL.z, oL.w);
        __half2 p2 = __floats2half2_rn(oH.x, oH.y);
        __half2 p3 = __floats2half2_rn(oH.z, oH.w);
        uint4 u;
        u.x = *(unsigned int*)&p0;
        u.y = *(unsigned int*)&p1;
        u.z = *(unsigned int*)&p2;
        u.w = *(unsigned int*)&p3;
        Hout[(size_t)node * 16 + lane] = u;
    } else {
        const float4* Wv = (const float4*)Wc;   // Wc[f][2]: float4 i = features 2i,2i+1
        float4 w0 = Wv[4 * lane];
        float4 w1 = Wv[4 * lane + 1];
        float4 w2 = Wv[4 * lane + 2];
        float4 w3 = Wv[4 * lane + 3];
        float p0 = oL.x * w0.x + oL.y * w0.z + oL.z * w1.x + oL.w * w1.z
                 + oH.x * w2.x + oH.y * w2.z + oH.z * w3.x + oH.w * w3.z;
        float p1 = oL.x * w0.y + oL.y * w0.w + oL.z * w1.y + oL.w * w1.w
                 + oH.x * w2.y + oH.y * w2.w + oH.z * w3.y + oH.w * w3.w;
#pragma unroll
        for (int d = 8; d >= 1; d >>= 1) {
            p0 += __shfl_down(p0, d, 16);
            p1 += __shfl_down(p1, d, 16);
        }
        if (lane == 0) {
            out[node * 2 + 0] = p0 + bc[0];
            out[node * 2 + 1] = p1 + bc[1];
        }
    }
}

// ---------------- launch ----------------

extern "C" void kernel_launch(void* const* d_in, const int* in_sizes, int n_in,
                              void* d_out, int out_size, void* d_ws, size_t ws_size,
                              hipStream_t stream) {
    const float* x   = (const float*)d_in[0];
    const int*   ei  = (const int*)d_in[1];
    const float* W1  = (const float*)d_in[2];
    const float* b1  = (const float*)d_in[3];
    const float* W2  = (const float*)d_in[4];
    const float* b2  = (const float*)d_in[5];
    const float* W3  = (const float*)d_in[6];
    const float* b3  = (const float*)d_in[7];
    const float* g1  = (const float*)d_in[8];
    const float* be1 = (const float*)d_in[9];
    const float* rm1 = (const float*)d_in[10];
    const float* rv1 = (const float*)d_in[11];
    const float* g2  = (const float*)d_in[12];
    const float* be2 = (const float*)d_in[13];
    const float* rm2 = (const float*)d_in[14];
    const float* rv2 = (const float*)d_in[15];
    const float* g3  = (const float*)d_in[16];
    const float* be3 = (const float*)d_in[17];
    const float* rm3 = (const float*)d_in[18];
    const float* rv3 = (const float*)d_in[19];
    const float* Wc  = (const float*)d_in[20];
    const float* bc  = (const float*)d_in[21];
    float* out = (float*)d_out;

    int n = in_sizes[0] / 128;
    int e = in_sizes[1] / 2;
    const int* src = ei;
    const int* dst = ei + e;

    char* ws = (char*)d_ws;
    size_t off = 0;
    auto alloc = [&](size_t bytes) -> char* {
        char* p = ws + off;
        off += (bytes + 255) & ~(size_t)255;
        return p;
    };
    int nA    = (e + CHUNK - 1) / CHUNK;
    int nbuck = (n + (1 << BBITS) - 1) >> BBITS;
    int tlen  = nbuck * nA;
    int erCap = e + (nbuck << 12) + 64;

    char*      buf0     = (char*) alloc((size_t)(n + 1) * 256);   // gemm out (ping)
    char*      buf1     = (char*) alloc((size_t)(n + 1) * 256);   // agg out (pong); bed aliases
    float*     dinv     = (float*)alloc((size_t)(n + 1) * 4);
    int2*      offs2    = (int2*) alloc((size_t)n * 8);
    int*       tableT   = (int*)  alloc((size_t)(tlen + 1) * 4);
    int*       parts    = (int*)  alloc(8192);
    int*       er       = (int*)  alloc((size_t)erCap * 4);
    _Float16*  pW       = (_Float16*)alloc(3 * 16384 * 2);
    (void)ws_size; (void)n_in; (void)out_size;

    // bed aliases buf1 (dead until agg1 writes; consumed by k_rank_gemm1)
    int2* bed = (int2*)buf1;                         // e*8 = 12.8 MB < 25.6 MB

    int nbT   = (tlen + 1023) / 1024;
    int gT    = (tlen + 255) / 256;
    int gGemm = (n + 63) / 64;
    int gAgg  = (n + 15) / 16;

    k_pack_hist<<<6 + nA, 1024, 0, stream>>>(W1, W2, W3, pW, dst, tableT, nA, nbuck, e);
    k_scan_block<<<nbT, 1024, 0, stream>>>(tableT, tableT, parts, tlen);
    k_scan_addp<<<gT, 256, 0, stream>>>(tableT, parts, tlen);
    k_scatter<<<nA, 1024, 0, stream>>>(src, dst, tableT, bed, nA, nbuck, e);
    // rank/finalize (196 blocks) ∥ layer-1 GEMM (1563 blocks, dinv-free)
    k_rank_gemm1<<<nbuck + gGemm, 256, 0, stream>>>(
        bed, tableT, offs2, er, dinv,
        (unsigned int*)(buf0 + (size_t)n * 256),
        x, pW, (uint4*)buf0, nA, nbuck, n, e);

    // layer 1: agg (buf0 unscaled -> buf1, SRC_SCALE)
    k_aggregate<false, true><<<gAgg, 256, 0, stream>>>(
        (const uint4*)buf0, offs2, er, dinv, b1, g1, be1, rm1, rv1,
        (uint4*)buf1, nullptr, nullptr, nullptr, n);
    // layer 2: gemm (buf1 -> buf0, ×dinv), agg (buf0 -> buf1)
    k_gemm_mfma<<<gGemm, 256, 0, stream>>>(buf1, pW + 16384, dinv, (uint4*)buf0, n);
    k_aggregate<false, false><<<gAgg, 256, 0, stream>>>(
        (const uint4*)buf0, offs2, er, dinv, b2, g2, be2, rm2, rv2,
        (uint4*)buf1, nullptr, nullptr, nullptr, n);
    // layer 3: gemm (buf1 -> buf0, ×dinv), agg + classifier (buf0 -> out)
    k_gemm_mfma<<<gGemm, 256, 0, stream>>>(buf1, pW + 32768, dinv, (uint4*)buf0, n);
    k_aggregate<true, false><<<gAgg, 256, 0, stream>>>(
        (const uint4*)buf0, offs2, er, dinv, b3, g3, be3, rm3, rv3,
        nullptr, Wc, bc, out, n);
}